// Round 9
// baseline (364.496 us; speedup 1.0000x reference)
//
#include <hip/hip_runtime.h>

typedef unsigned short u16;
typedef unsigned int u32;
typedef __attribute__((ext_vector_type(8))) short bf16x8;
typedef __attribute__((ext_vector_type(4))) float f32x4;
typedef __attribute__((ext_vector_type(4))) unsigned short u16x4;

#define MFMA16(a,b,c) __builtin_amdgcn_mfma_f32_16x16x32_bf16((a),(b),(c),0,0,0)

__device__ __forceinline__ u16 f2b(float f){
  union { float f; u32 u; } x; x.f = f;
  u32 r = x.u + 0x7fffu + ((x.u >> 16) & 1u);
  return (u16)(r >> 16);
}
__device__ __forceinline__ float b2f(u16 u){
  union { u32 u; float f; } x; x.u = ((u32)u) << 16; return x.f;
}

// ---------------- elementwise f32 -> bf16, vectorized x4 ----------------
__global__ void cvt_bf16(const float* __restrict__ in, u16* __restrict__ out, int n4){
  int i = blockIdx.x * blockDim.x + threadIdx.x;
  int stride = gridDim.x * blockDim.x;
  for (; i < n4; i += stride){
    f32x4 v = ((const f32x4*)in)[i];
    u16x4 o = { f2b(v.x), f2b(v.y), f2b(v.z), f2b(v.w) };
    ((u16x4*)out)[i] = o;
  }
}

// ------- LDS-tiled transpose + convert: f32 [K][inLd] -> bf16 [N][outLd] -------
__global__ void transpose_cvt(const float* __restrict__ in, u16* __restrict__ out,
                              int inLd, int outLd){
  __shared__ __align__(16) float tile[64][68];
  int n0 = blockIdx.x * 64, k0 = blockIdx.y * 64;
  int t = threadIdx.x;
  int r = t & 63, cg = t >> 6;
  for (int j = 0; j < 4; ++j){
    int c = cg * 4 + j * 16;
    f32x4 v = *(const f32x4*)&in[(size_t)(k0 + r) * inLd + n0 + c];
    *(f32x4*)&tile[r][c] = v;
  }
  __syncthreads();
  for (int j = 0; j < 4; ++j){
    int c = cg * 4 + j * 16;
    u16x4 o = { f2b(tile[c+0][r]), f2b(tile[c+1][r]), f2b(tile[c+2][r]), f2b(tile[c+3][r]) };
    *(u16x4*)&out[(size_t)(n0 + r) * outLd + k0 + c] = o;
  }
}

// ------- bf16 transpose for V: qkv[t][2560 + kh*128 + d] -> vt[kh][d][t] -------
__global__ void transpose_v(const u16* __restrict__ qkv, u16* __restrict__ vt){
  __shared__ __align__(16) u16 tile[64][72];
  int t0 = blockIdx.x * 64, d0 = blockIdx.y * 64, kh = blockIdx.z;
  int tt = threadIdx.x;
  int r = tt & 63, cg = tt >> 6;
  for (int j = 0; j < 2; ++j){
    int c = cg * 8 + j * 32;
    *(bf16x8*)&tile[r][c] = *(const bf16x8*)&qkv[(size_t)(t0 + r) * 3072 + 2560 + kh*128 + d0 + c];
  }
  __syncthreads();
  for (int j = 0; j < 2; ++j){
    int c = cg * 8 + j * 32;
    bf16x8 o = { (short)tile[c+0][r], (short)tile[c+1][r], (short)tile[c+2][r], (short)tile[c+3][r],
                 (short)tile[c+4][r], (short)tile[c+5][r], (short)tile[c+6][r], (short)tile[c+7][r] };
    *(bf16x8*)&vt[(size_t)(kh*128 + d0 + r) * 2048 + t0 + c] = o;
  }
}

// ------- bf16 MFMA GEMM (m97 structure): C = A[M][K] * Bt[N][K]^T, 128x128 tile, BK=64, global_load_lds -------
template<bool BF16OUT>
__global__ __launch_bounds__(256) void gemm_bt(const u16* __restrict__ A, const u16* __restrict__ Bt,
                                               void* __restrict__ Cv, int M, int N, int K){
  __shared__ __align__(16) u16 Alds[128*64];
  __shared__ __align__(16) u16 Blds[128*64];
  int m0 = blockIdx.y * 128, n0 = blockIdx.x * 128;
  int t = threadIdx.x;
  int lane = t & 63, wid = t >> 6;
  int wr = wid >> 1, wc = wid & 1;
  int r16 = lane & 15, g = lane >> 4;
  f32x4 acc[4][4] = {};
  int off = (wid * 4) * 512 + lane * 8;
  for (int kb = 0; kb < K; kb += 64){
    #pragma unroll
    for (int i = 0; i < 4; ++i){
      int o = off + i * 512;
      int row = o >> 6, col = o & 63;
      __builtin_amdgcn_global_load_lds(
        (const __attribute__((address_space(1))) void*)&A[(size_t)(m0 + row) * K + kb + col],
        (__attribute__((address_space(3))) void*)&Alds[(wid*4 + i) * 512], 16, 0, 0);
    }
    #pragma unroll
    for (int i = 0; i < 4; ++i){
      int o = off + i * 512;
      int row = o >> 6, col = o & 63;
      __builtin_amdgcn_global_load_lds(
        (const __attribute__((address_space(1))) void*)&Bt[(size_t)(n0 + row) * K + kb + col],
        (__attribute__((address_space(3))) void*)&Blds[(wid*4 + i) * 512], 16, 0, 0);
    }
    __syncthreads();
    #pragma unroll
    for (int kc = 0; kc < 2; ++kc){
      bf16x8 af[4], bfr[4];
      #pragma unroll
      for (int mi = 0; mi < 4; ++mi)
        af[mi] = *(const bf16x8*)&Alds[(wr*64 + mi*16 + r16) * 64 + kc*32 + g*8];
      #pragma unroll
      for (int ni = 0; ni < 4; ++ni)
        bfr[ni] = *(const bf16x8*)&Blds[(wc*64 + ni*16 + r16) * 64 + kc*32 + g*8];
      #pragma unroll
      for (int mi = 0; mi < 4; ++mi)
        #pragma unroll
        for (int ni = 0; ni < 4; ++ni)
          acc[mi][ni] = MFMA16(af[mi], bfr[ni], acc[mi][ni]);
    }
    __syncthreads();
  }
  #pragma unroll
  for (int mi = 0; mi < 4; ++mi)
    #pragma unroll
    for (int ni = 0; ni < 4; ++ni){
      int row0 = m0 + wr*64 + mi*16 + g*4;
      int col  = n0 + wc*64 + ni*16 + r16;
      #pragma unroll
      for (int r = 0; r < 4; ++r){
        float v = acc[mi][ni][r];
        if (BF16OUT) ((u16*)Cv)[(size_t)(row0 + r) * N + col] = f2b(v);
        else         ((float*)Cv)[(size_t)(row0 + r) * N + col] = v;
      }
    }
}

// ------- RoPE cos/sin table: tab[t][e] = {cos,sin}(p * 10000^(-e/64) * rs), 131072 entries -------
__global__ void build_rope_tab(const float* __restrict__ rsp, const int* __restrict__ pop,
                               float2* __restrict__ tab){
  int i = blockIdx.x * blockDim.x + threadIdx.x;   // 0..131071
  int t = i >> 6, e = i & 63;
  int p = pop[0] + t;
  double invf = exp((double)e * -0.14391156381125648);   // -ln(10000)/64
  double ang = fmod((double)p * invf * (double)rsp[0], 6.283185307179586476925286766559);
  float fa = (float)ang;
  tab[i] = make_float2(cosf(fa), sinf(fa));
}

// ------- RoPE (q,k only), table-driven: qkv bf16 [T][3072] -> q[16][T][128], k[4][T][128] -------
__global__ void rope_kernel(const u16* __restrict__ qkv, u16* __restrict__ qb, u16* __restrict__ kb,
                            const float2* __restrict__ tab){
  int t = blockIdx.x;
  const u16* row = qkv + (size_t)t * 3072;
  const float2* trow = tab + t * 64;
  for (int idx = threadIdx.x; idx < 2560; idx += blockDim.x){
    int h = idx >> 7, d = idx & 127;
    const u16* hp = row + (h << 7);
    int e = d & 63;
    float2 cs = trow[e];
    float v;
    if (d < 64) v = b2f(hp[d]) * cs.x - b2f(hp[2*d+1]) * cs.y;
    else        v = b2f(hp[d]) * cs.x + b2f(hp[2*e]) * cs.y;
    u16 o = f2b(v);
    if (h < 16) qb[((size_t)(h*2048 + t))*128 + d] = o;
    else        kb[((size_t)((h-16)*2048 + t))*128 + d] = o;
  }
}

// ------- flash attention v4: block = (q-tile32, head); 4 waves split KV by (tile mod 4); LDS tree-combine -------
// No-max softmax (bounded scores) makes per-wave partials (acc, l) elementwise-additive per lane.
// S^T = mfma(K, Q): lane holds q = lane&15, k = tile*32 + half*16 + g*4 + r  (g = lane>>4)
// O = mfma(P, Vt): P via per-wave LDS; Vt[d][t] global, contiguous 16B B-frags.
__global__ __launch_bounds__(256, 2) void attn_kernel(const u16* __restrict__ qb, const u16* __restrict__ kb,
                                                      const u16* __restrict__ vt, u16* __restrict__ attn2){
  __shared__ __align__(16) u16 P4[4][2][16][40];
  __shared__ float red[2][64][66];
  int h = blockIdx.y, kh = h >> 2;
  int t = threadIdx.x, lane = t & 63, wid = t >> 6;
  int r16 = lane & 15, g = lane >> 4;
  int qt32 = 63 - blockIdx.x;                    // largest work first
  int qbase = qt32 * 32;

  bf16x8 qf0[4], qf1[4];
  const u16* q0p = qb + ((size_t)(h*2048 + qbase + r16)) * 128;
  #pragma unroll
  for (int dc = 0; dc < 4; ++dc){
    qf0[dc] = *(const bf16x8*)&q0p[dc*32 + g*8];
    qf1[dc] = *(const bf16x8*)&q0p[16*128 + dc*32 + g*8];
  }

  const u16* kbase = kb + (size_t)kh * 2048 * 128;
  const u16* vbase = vt + (size_t)kh * 128 * 2048;

  float l0 = 0.f, l1 = 0.f;                      // per-lane partial denominators
  f32x4 acc0[8] = {}, acc1[8] = {};
  const float scale = 0.08838834764831845f;      // 128^-0.5

  auto LOADK = [&](bf16x8 (&kr)[8], int tile){
    const u16* kp = kbase + (size_t)(tile*32 + r16) * 128;
    #pragma unroll
    for (int dc = 0; dc < 4; ++dc){
      kr[dc]     = *(const bf16x8*)&kp[dc*32 + g*8];
      kr[4 + dc] = *(const bf16x8*)&kp[16*128 + dc*32 + g*8];
    }
  };

  auto COMPUTE = [&](bf16x8 (&kr)[8], int tile){
    bf16x8 vr[8];
    int kcol = tile*32 + g*8;
    #pragma unroll
    for (int dt = 0; dt < 8; ++dt)
      vr[dt] = *(const bf16x8*)&vbase[(size_t)(dt*16 + r16) * 2048 + kcol];
    f32x4 sA0 = {0.f,0.f,0.f,0.f}, sA1 = {0.f,0.f,0.f,0.f};
    f32x4 sB0 = {0.f,0.f,0.f,0.f}, sB1 = {0.f,0.f,0.f,0.f};
    #pragma unroll
    for (int dc = 0; dc < 4; ++dc){
      sA0 = MFMA16(kr[dc],   qf0[dc], sA0);
      sA1 = MFMA16(kr[dc],   qf1[dc], sA1);
      sB0 = MFMA16(kr[4+dc], qf0[dc], sB0);
      sB1 = MFMA16(kr[4+dc], qf1[dc], sB1);
    }
    float x0[8], x1[8];
    #pragma unroll
    for (int r = 0; r < 4; ++r){
      x0[r] = sA0[r] * scale; x0[4+r] = sB0[r] * scale;
      x1[r] = sA1[r] * scale; x1[4+r] = sB1[r] * scale;
    }
    if (tile == qt32){                           // diagonal tile -> causal mask
      int q0r = qbase + r16, q1r = q0r + 16;
      #pragma unroll
      for (int hf = 0; hf < 2; ++hf)
        #pragma unroll
        for (int r = 0; r < 4; ++r){
          int k = tile*32 + hf*16 + g*4 + r;
          if (k > q0r) x0[hf*4 + r] = -1e30f;
          if (k > q1r) x1[hf*4 + r] = -1e30f;
        }
    }
    float ps0 = 0.f, ps1 = 0.f;
    #pragma unroll
    for (int j = 0; j < 8; ++j){
      x0[j] = __expf(x0[j]); ps0 += x0[j];
      x1[j] = __expf(x1[j]); ps1 += x1[j];
    }
    l0 += ps0; l1 += ps1;
    u16x4 a0 = { f2b(x0[0]), f2b(x0[1]), f2b(x0[2]), f2b(x0[3]) };
    u16x4 b0 = { f2b(x0[4]), f2b(x0[5]), f2b(x0[6]), f2b(x0[7]) };
    u16x4 a1 = { f2b(x1[0]), f2b(x1[1]), f2b(x1[2]), f2b(x1[3]) };
    u16x4 b1 = { f2b(x1[4]), f2b(x1[5]), f2b(x1[6]), f2b(x1[7]) };
    *(u16x4*)&P4[wid][0][r16][g*4]      = a0;
    *(u16x4*)&P4[wid][0][r16][16+g*4]   = b0;
    *(u16x4*)&P4[wid][1][r16][g*4]      = a1;
    *(u16x4*)&P4[wid][1][r16][16+g*4]   = b1;
    asm volatile("s_waitcnt lgkmcnt(0)" ::: "memory");   // wave-internal RAW fence
    bf16x8 pa0 = *(const bf16x8*)&P4[wid][0][r16][g*8];
    bf16x8 pa1 = *(const bf16x8*)&P4[wid][1][r16][g*8];
    #pragma unroll
    for (int dt = 0; dt < 8; ++dt){
      acc0[dt] = MFMA16(pa0, vr[dt], acc0[dt]);
      acc1[dt] = MFMA16(pa1, vr[dt], acc1[dt]);
    }
  };

  // this wave's KV tiles: wid, wid+4, ... <= qt32; K double-buffered (static reg arrays)
  int nj = (wid <= qt32) ? ((qt32 - wid) >> 2) + 1 : 0;
  bf16x8 kA[8], kB[8];
  if (nj > 0) LOADK(kA, wid);
  int j = 0;
  while (j < nj){
    if (j + 1 < nj) LOADK(kB, wid + 4*(j+1));
    COMPUTE(kA, wid + 4*j);
    ++j; if (j >= nj) break;
    if (j + 1 < nj) LOADK(kA, wid + 4*(j+1));
    COMPUTE(kB, wid + 4*j);
    ++j;
  }

  // ---- cross-wave combine: partials are additive (no-max softmax) ----
  if (wid >= 2){
    int s = wid - 2;
    #pragma unroll
    for (int dt = 0; dt < 8; ++dt)
      #pragma unroll
      for (int r = 0; r < 4; ++r){
        red[s][lane][dt*4 + r]      = acc0[dt][r];
        red[s][lane][32 + dt*4 + r] = acc1[dt][r];
      }
    red[s][lane][64] = l0; red[s][lane][65] = l1;
  }
  __syncthreads();
  if (wid < 2){
    #pragma unroll
    for (int dt = 0; dt < 8; ++dt)
      #pragma unroll
      for (int r = 0; r < 4; ++r){
        acc0[dt][r] += red[wid][lane][dt*4 + r];
        acc1[dt][r] += red[wid][lane][32 + dt*4 + r];
      }
    l0 += red[wid][lane][64]; l1 += red[wid][lane][65];
  }
  __syncthreads();
  if (wid == 1){
    #pragma unroll
    for (int dt = 0; dt < 8; ++dt)
      #pragma unroll
      for (int r = 0; r < 4; ++r){
        red[0][lane][dt*4 + r]      = acc0[dt][r];
        red[0][lane][32 + dt*4 + r] = acc1[dt][r];
      }
    red[0][lane][64] = l0; red[0][lane][65] = l1;
  }
  __syncthreads();
  if (wid == 0){
    #pragma unroll
    for (int dt = 0; dt < 8; ++dt)
      #pragma unroll
      for (int r = 0; r < 4; ++r){
        acc0[dt][r] += red[0][lane][dt*4 + r];
        acc1[dt][r] += red[0][lane][32 + dt*4 + r];
      }
    l0 += red[0][lane][64]; l1 += red[0][lane][65];
    // group-reduce l (the only cross-lane ops in the kernel)
    l0 += __shfl_xor(l0, 16); l0 += __shfl_xor(l0, 32);
    l1 += __shfl_xor(l1, 16); l1 += __shfl_xor(l1, 32);
    float rq0[4], rq1[4];
    #pragma unroll
    for (int r = 0; r < 4; ++r){
      rq0[r] = 1.f / __shfl(l0, g*4 + r);
      rq1[r] = 1.f / __shfl(l1, g*4 + r);
    }
    #pragma unroll
    for (int dt = 0; dt < 8; ++dt)
      #pragma unroll
      for (int r = 0; r < 4; ++r){
        attn2[(size_t)(qbase + g*4 + r)      * 2048 + h*128 + dt*16 + r16] = f2b(acc0[dt][r] * rq0[r]);
        attn2[(size_t)(qbase + 16 + g*4 + r) * 2048 + h*128 + dt*16 + r16] = f2b(acc1[dt][r] * rq1[r]);
      }
  }
}

extern "C" void kernel_launch(void* const* d_in, const int* in_sizes, int n_in,
                              void* d_out, int out_size, void* d_ws, size_t ws_size,
                              hipStream_t stream) {
  const float* x   = (const float*)d_in[0];
  // d_in[1] = mask (deterministic causal triu(k=1) -> handled arithmetically)
  const float* Wq  = (const float*)d_in[2];
  const float* Wk  = (const float*)d_in[3];
  const float* Wv  = (const float*)d_in[4];
  const float* Wo  = (const float*)d_in[5];
  const float* rs  = (const float*)d_in[6];
  const int*   po  = (const int*)d_in[7];
  float* out = (float*)d_out;

  u16* ws    = (u16*)d_ws;
  u16* xb    = ws;                       // [2048][2048]      bf16 (dead after gemm1; reused for rope table)
  u16* wqkv  = xb   + 4194304;           // [3072][2048] B^T  bf16
  u16* wo_t  = wqkv + 6291456;           // [2048][2048] B^T  bf16
  u16* qkv   = wo_t + 4194304;           // [2048][3072]      bf16
  u16* qb    = qkv  + 6291456;           // [16][2048][128]   bf16
  u16* kb2   = qb   + 4194304;           // [4][2048][128]    bf16
  u16* vt    = kb2  + 1048576;           // [4][128][2048]    bf16 (V transposed)
  u16* attn2 = vt   + 1048576;           // [2048][2048]      bf16
  float2* tab = (float2*)xb;             // [2048][64] cos/sin (1 MB, in dead xb region)

  cvt_bf16<<<2048, 256, 0, stream>>>(x, xb, 1048576);
  transpose_cvt<<<dim3(32,32), 256, 0, stream>>>(Wq, wqkv,             2048, 2048);
  transpose_cvt<<<dim3(8, 32), 256, 0, stream>>>(Wk, wqkv + 2048*2048, 512,  2048);
  transpose_cvt<<<dim3(8, 32), 256, 0, stream>>>(Wv, wqkv + 2560*2048, 512,  2048);
  transpose_cvt<<<dim3(32,32), 256, 0, stream>>>(Wo, wo_t,             2048, 2048);

  gemm_bt<true><<<dim3(24,16), 256, 0, stream>>>(xb, wqkv, qkv, 2048, 3072, 2048);
  build_rope_tab<<<512, 256, 0, stream>>>(rs, po, tab);
  rope_kernel<<<2048, 256, 0, stream>>>(qkv, qb, kb2, tab);
  transpose_v<<<dim3(32,2,4), 256, 0, stream>>>(qkv, vt);
  attn_kernel<<<dim3(64,16), 256, 0, stream>>>(qb, kb2, vt, attn2);
  gemm_bt<false><<<dim3(16,16), 256, 0, stream>>>(attn2, wo_t, out, 2048, 2048, 2048);
}

// Round 13
// 361.891 us; speedup vs baseline: 1.0072x; 1.0072x over previous
//
#include <hip/hip_runtime.h>

typedef unsigned short u16;
typedef unsigned int u32;
typedef __attribute__((ext_vector_type(8))) short bf16x8;
typedef __attribute__((ext_vector_type(4))) float f32x4;
typedef __attribute__((ext_vector_type(4))) unsigned short u16x4;

#define MFMA16(a,b,c) __builtin_amdgcn_mfma_f32_16x16x32_bf16((a),(b),(c),0,0,0)

__device__ __forceinline__ u16 f2b(float f){
  union { float f; u32 u; } x; x.f = f;
  u32 r = x.u + 0x7fffu + ((x.u >> 16) & 1u);
  return (u16)(r >> 16);
}
__device__ __forceinline__ float b2f(u16 u){
  union { u32 u; float f; } x; x.u = ((u32)u) << 16; return x.f;
}

// ---------------- elementwise f32 -> bf16, vectorized x4 ----------------
__global__ void cvt_bf16(const float* __restrict__ in, u16* __restrict__ out, int n4){
  int i = blockIdx.x * blockDim.x + threadIdx.x;
  int stride = gridDim.x * blockDim.x;
  for (; i < n4; i += stride){
    f32x4 v = ((const f32x4*)in)[i];
    u16x4 o = { f2b(v.x), f2b(v.y), f2b(v.z), f2b(v.w) };
    ((u16x4*)out)[i] = o;
  }
}

// ------- LDS-tiled transpose + convert: f32 [K][inLd] -> bf16 [N][outLd] -------
__global__ void transpose_cvt(const float* __restrict__ in, u16* __restrict__ out,
                              int inLd, int outLd){
  __shared__ __align__(16) float tile[64][68];
  int n0 = blockIdx.x * 64, k0 = blockIdx.y * 64;
  int t = threadIdx.x;
  int r = t & 63, cg = t >> 6;
  for (int j = 0; j < 4; ++j){
    int c = cg * 4 + j * 16;
    f32x4 v = *(const f32x4*)&in[(size_t)(k0 + r) * inLd + n0 + c];
    *(f32x4*)&tile[r][c] = v;
  }
  __syncthreads();
  for (int j = 0; j < 4; ++j){
    int c = cg * 4 + j * 16;
    u16x4 o = { f2b(tile[c+0][r]), f2b(tile[c+1][r]), f2b(tile[c+2][r]), f2b(tile[c+3][r]) };
    *(u16x4*)&out[(size_t)(n0 + r) * outLd + k0 + c] = o;
  }
}

// ------- bf16 transpose for V: qkv[t][2560 + kh*128 + d] -> vt[kh][d][t] -------
__global__ void transpose_v(const u16* __restrict__ qkv, u16* __restrict__ vt){
  __shared__ __align__(16) u16 tile[64][72];
  int t0 = blockIdx.x * 64, d0 = blockIdx.y * 64, kh = blockIdx.z;
  int tt = threadIdx.x;
  int r = tt & 63, cg = tt >> 6;
  for (int j = 0; j < 2; ++j){
    int c = cg * 8 + j * 32;
    *(bf16x8*)&tile[r][c] = *(const bf16x8*)&qkv[(size_t)(t0 + r) * 3072 + 2560 + kh*128 + d0 + c];
  }
  __syncthreads();
  for (int j = 0; j < 2; ++j){
    int c = cg * 8 + j * 32;
    bf16x8 o = { (short)tile[c+0][r], (short)tile[c+1][r], (short)tile[c+2][r], (short)tile[c+3][r],
                 (short)tile[c+4][r], (short)tile[c+5][r], (short)tile[c+6][r], (short)tile[c+7][r] };
    *(bf16x8*)&vt[(size_t)(kh*128 + d0 + r) * 2048 + t0 + c] = o;
  }
}

// ------- bf16 MFMA GEMM (m97 structure): C = A[M][K] * Bt[N][K]^T, 128x128 tile, BK=64, global_load_lds -------
template<bool BF16OUT>
__global__ __launch_bounds__(256) void gemm_bt(const u16* __restrict__ A, const u16* __restrict__ Bt,
                                               void* __restrict__ Cv, int M, int N, int K){
  __shared__ __align__(16) u16 Alds[128*64];
  __shared__ __align__(16) u16 Blds[128*64];
  int m0 = blockIdx.y * 128, n0 = blockIdx.x * 128;
  int t = threadIdx.x;
  int lane = t & 63, wid = t >> 6;
  int wr = wid >> 1, wc = wid & 1;
  int r16 = lane & 15, g = lane >> 4;
  f32x4 acc[4][4] = {};
  int off = (wid * 4) * 512 + lane * 8;
  for (int kb = 0; kb < K; kb += 64){
    #pragma unroll
    for (int i = 0; i < 4; ++i){
      int o = off + i * 512;
      int row = o >> 6, col = o & 63;
      __builtin_amdgcn_global_load_lds(
        (const __attribute__((address_space(1))) void*)&A[(size_t)(m0 + row) * K + kb + col],
        (__attribute__((address_space(3))) void*)&Alds[(wid*4 + i) * 512], 16, 0, 0);
    }
    #pragma unroll
    for (int i = 0; i < 4; ++i){
      int o = off + i * 512;
      int row = o >> 6, col = o & 63;
      __builtin_amdgcn_global_load_lds(
        (const __attribute__((address_space(1))) void*)&Bt[(size_t)(n0 + row) * K + kb + col],
        (__attribute__((address_space(3))) void*)&Blds[(wid*4 + i) * 512], 16, 0, 0);
    }
    __syncthreads();
    #pragma unroll
    for (int kc = 0; kc < 2; ++kc){
      bf16x8 af[4], bfr[4];
      #pragma unroll
      for (int mi = 0; mi < 4; ++mi)
        af[mi] = *(const bf16x8*)&Alds[(wr*64 + mi*16 + r16) * 64 + kc*32 + g*8];
      #pragma unroll
      for (int ni = 0; ni < 4; ++ni)
        bfr[ni] = *(const bf16x8*)&Blds[(wc*64 + ni*16 + r16) * 64 + kc*32 + g*8];
      #pragma unroll
      for (int mi = 0; mi < 4; ++mi)
        #pragma unroll
        for (int ni = 0; ni < 4; ++ni)
          acc[mi][ni] = MFMA16(af[mi], bfr[ni], acc[mi][ni]);
    }
    __syncthreads();
  }
  #pragma unroll
  for (int mi = 0; mi < 4; ++mi)
    #pragma unroll
    for (int ni = 0; ni < 4; ++ni){
      int row0 = m0 + wr*64 + mi*16 + g*4;
      int col  = n0 + wc*64 + ni*16 + r16;
      #pragma unroll
      for (int r = 0; r < 4; ++r){
        float v = acc[mi][ni][r];
        if (BF16OUT) ((u16*)Cv)[(size_t)(row0 + r) * N + col] = f2b(v);
        else         ((float*)Cv)[(size_t)(row0 + r) * N + col] = v;
      }
    }
}

// ------- RoPE cos/sin table: tab[t][e] = {cos,sin}(p * 10000^(-e/64) * rs), 131072 entries -------
__global__ void build_rope_tab(const float* __restrict__ rsp, const int* __restrict__ pop,
                               float2* __restrict__ tab){
  int i = blockIdx.x * blockDim.x + threadIdx.x;   // 0..131071
  int t = i >> 6, e = i & 63;
  int p = pop[0] + t;
  double invf = exp((double)e * -0.14391156381125648);   // -ln(10000)/64
  double ang = fmod((double)p * invf * (double)rsp[0], 6.283185307179586476925286766559);
  float fa = (float)ang;
  tab[i] = make_float2(cosf(fa), sinf(fa));
}

// ------- RoPE (q,k only), table-driven: qkv bf16 [T][3072] -> q[16][T][128], k[4][T][128] -------
__global__ void rope_kernel(const u16* __restrict__ qkv, u16* __restrict__ qb, u16* __restrict__ kb,
                            const float2* __restrict__ tab){
  int t = blockIdx.x;
  const u16* row = qkv + (size_t)t * 3072;
  const float2* trow = tab + t * 64;
  for (int idx = threadIdx.x; idx < 2560; idx += blockDim.x){
    int h = idx >> 7, d = idx & 127;
    const u16* hp = row + (h << 7);
    int e = d & 63;
    float2 cs = trow[e];
    float v;
    if (d < 64) v = b2f(hp[d]) * cs.x - b2f(hp[2*d+1]) * cs.y;
    else        v = b2f(hp[d]) * cs.x + b2f(hp[2*e]) * cs.y;
    u16 o = f2b(v);
    if (h < 16) qb[((size_t)(h*2048 + t))*128 + d] = o;
    else        kb[((size_t)((h-16)*2048 + t))*128 + d] = o;
  }
}

// ------- flash attention v4.1: same structure as v4, but NO forced 2-blocks/CU --------
// (v4 regression root-cause: __launch_bounds__(256,2) capped VGPR at 128 -> accumulator
//  spills to scratch. At natural ~192+ VGPR the HW reaches 2 blocks/CU anyway.)
__global__ __launch_bounds__(256, 1) void attn_kernel(const u16* __restrict__ qb, const u16* __restrict__ kb,
                                                      const u16* __restrict__ vt, u16* __restrict__ attn2){
  __shared__ __align__(16) u16 P4[4][2][16][40];
  __shared__ float red[2][64][66];
  int h = blockIdx.y, kh = h >> 2;
  int t = threadIdx.x, lane = t & 63, wid = t >> 6;
  int r16 = lane & 15, g = lane >> 4;
  int qt32 = 63 - blockIdx.x;                    // largest work first
  int qbase = qt32 * 32;

  bf16x8 qf0[4], qf1[4];
  const u16* q0p = qb + ((size_t)(h*2048 + qbase + r16)) * 128;
  #pragma unroll
  for (int dc = 0; dc < 4; ++dc){
    qf0[dc] = *(const bf16x8*)&q0p[dc*32 + g*8];
    qf1[dc] = *(const bf16x8*)&q0p[16*128 + dc*32 + g*8];
  }

  const u16* kbase = kb + (size_t)kh * 2048 * 128;
  const u16* vbase = vt + (size_t)kh * 128 * 2048;

  float l0 = 0.f, l1 = 0.f;                      // per-lane partial denominators
  f32x4 acc0[8] = {}, acc1[8] = {};
  const float scale = 0.08838834764831845f;      // 128^-0.5

  auto LOADK = [&](bf16x8 (&kr)[8], int tile){
    const u16* kp = kbase + (size_t)(tile*32 + r16) * 128;
    #pragma unroll
    for (int dc = 0; dc < 4; ++dc){
      kr[dc]     = *(const bf16x8*)&kp[dc*32 + g*8];
      kr[4 + dc] = *(const bf16x8*)&kp[16*128 + dc*32 + g*8];
    }
  };

  auto COMPUTE = [&](bf16x8 (&kr)[8], int tile){
    bf16x8 vr[8];
    int kcol = tile*32 + g*8;
    #pragma unroll
    for (int dt = 0; dt < 8; ++dt)
      vr[dt] = *(const bf16x8*)&vbase[(size_t)(dt*16 + r16) * 2048 + kcol];
    f32x4 sA0 = {0.f,0.f,0.f,0.f}, sA1 = {0.f,0.f,0.f,0.f};
    f32x4 sB0 = {0.f,0.f,0.f,0.f}, sB1 = {0.f,0.f,0.f,0.f};
    #pragma unroll
    for (int dc = 0; dc < 4; ++dc){
      sA0 = MFMA16(kr[dc],   qf0[dc], sA0);
      sA1 = MFMA16(kr[dc],   qf1[dc], sA1);
      sB0 = MFMA16(kr[4+dc], qf0[dc], sB0);
      sB1 = MFMA16(kr[4+dc], qf1[dc], sB1);
    }
    float x0[8], x1[8];
    #pragma unroll
    for (int r = 0; r < 4; ++r){
      x0[r] = sA0[r] * scale; x0[4+r] = sB0[r] * scale;
      x1[r] = sA1[r] * scale; x1[4+r] = sB1[r] * scale;
    }
    if (tile == qt32){                           // diagonal tile -> causal mask
      int q0r = qbase + r16, q1r = q0r + 16;
      #pragma unroll
      for (int hf = 0; hf < 2; ++hf)
        #pragma unroll
        for (int r = 0; r < 4; ++r){
          int k = tile*32 + hf*16 + g*4 + r;
          if (k > q0r) x0[hf*4 + r] = -1e30f;
          if (k > q1r) x1[hf*4 + r] = -1e30f;
        }
    }
    float ps0 = 0.f, ps1 = 0.f;
    #pragma unroll
    for (int j = 0; j < 8; ++j){
      x0[j] = __expf(x0[j]); ps0 += x0[j];
      x1[j] = __expf(x1[j]); ps1 += x1[j];
    }
    l0 += ps0; l1 += ps1;
    u16x4 a0 = { f2b(x0[0]), f2b(x0[1]), f2b(x0[2]), f2b(x0[3]) };
    u16x4 b0 = { f2b(x0[4]), f2b(x0[5]), f2b(x0[6]), f2b(x0[7]) };
    u16x4 a1 = { f2b(x1[0]), f2b(x1[1]), f2b(x1[2]), f2b(x1[3]) };
    u16x4 b1 = { f2b(x1[4]), f2b(x1[5]), f2b(x1[6]), f2b(x1[7]) };
    *(u16x4*)&P4[wid][0][r16][g*4]      = a0;
    *(u16x4*)&P4[wid][0][r16][16+g*4]   = b0;
    *(u16x4*)&P4[wid][1][r16][g*4]      = a1;
    *(u16x4*)&P4[wid][1][r16][16+g*4]   = b1;
    asm volatile("s_waitcnt lgkmcnt(0)" ::: "memory");   // wave-internal RAW fence
    bf16x8 pa0 = *(const bf16x8*)&P4[wid][0][r16][g*8];
    bf16x8 pa1 = *(const bf16x8*)&P4[wid][1][r16][g*8];
    #pragma unroll
    for (int dt = 0; dt < 8; ++dt){
      acc0[dt] = MFMA16(pa0, vr[dt], acc0[dt]);
      acc1[dt] = MFMA16(pa1, vr[dt], acc1[dt]);
    }
  };

  // this wave's KV tiles: wid, wid+4, ... <= qt32; K double-buffered (static reg arrays)
  int nj = (wid <= qt32) ? ((qt32 - wid) >> 2) + 1 : 0;
  bf16x8 kA[8], kB[8];
  if (nj > 0) LOADK(kA, wid);
  int j = 0;
  while (j < nj){
    if (j + 1 < nj) LOADK(kB, wid + 4*(j+1));
    COMPUTE(kA, wid + 4*j);
    ++j; if (j >= nj) break;
    if (j + 1 < nj) LOADK(kA, wid + 4*(j+1));
    COMPUTE(kB, wid + 4*j);
    ++j;
  }

  // ---- cross-wave combine: partials are additive (no-max softmax) ----
  if (wid >= 2){
    int s = wid - 2;
    #pragma unroll
    for (int dt = 0; dt < 8; ++dt)
      #pragma unroll
      for (int r = 0; r < 4; ++r){
        red[s][lane][dt*4 + r]      = acc0[dt][r];
        red[s][lane][32 + dt*4 + r] = acc1[dt][r];
      }
    red[s][lane][64] = l0; red[s][lane][65] = l1;
  }
  __syncthreads();
  if (wid < 2){
    #pragma unroll
    for (int dt = 0; dt < 8; ++dt)
      #pragma unroll
      for (int r = 0; r < 4; ++r){
        acc0[dt][r] += red[wid][lane][dt*4 + r];
        acc1[dt][r] += red[wid][lane][32 + dt*4 + r];
      }
    l0 += red[wid][lane][64]; l1 += red[wid][lane][65];
  }
  __syncthreads();
  if (wid == 1){
    #pragma unroll
    for (int dt = 0; dt < 8; ++dt)
      #pragma unroll
      for (int r = 0; r < 4; ++r){
        red[0][lane][dt*4 + r]      = acc0[dt][r];
        red[0][lane][32 + dt*4 + r] = acc1[dt][r];
      }
    red[0][lane][64] = l0; red[0][lane][65] = l1;
  }
  __syncthreads();
  if (wid == 0){
    #pragma unroll
    for (int dt = 0; dt < 8; ++dt)
      #pragma unroll
      for (int r = 0; r < 4; ++r){
        acc0[dt][r] += red[0][lane][dt*4 + r];
        acc1[dt][r] += red[0][lane][32 + dt*4 + r];
      }
    l0 += red[0][lane][64]; l1 += red[0][lane][65];
    // group-reduce l (the only cross-lane ops in the kernel)
    l0 += __shfl_xor(l0, 16); l0 += __shfl_xor(l0, 32);
    l1 += __shfl_xor(l1, 16); l1 += __shfl_xor(l1, 32);
    float rq0[4], rq1[4];
    #pragma unroll
    for (int r = 0; r < 4; ++r){
      rq0[r] = 1.f / __shfl(l0, g*4 + r);
      rq1[r] = 1.f / __shfl(l1, g*4 + r);
    }
    #pragma unroll
    for (int dt = 0; dt < 8; ++dt)
      #pragma unroll
      for (int r = 0; r < 4; ++r){
        attn2[(size_t)(qbase + g*4 + r)      * 2048 + h*128 + dt*16 + r16] = f2b(acc0[dt][r] * rq0[r]);
        attn2[(size_t)(qbase + 16 + g*4 + r) * 2048 + h*128 + dt*16 + r16] = f2b(acc1[dt][r] * rq1[r]);
      }
  }
}

extern "C" void kernel_launch(void* const* d_in, const int* in_sizes, int n_in,
                              void* d_out, int out_size, void* d_ws, size_t ws_size,
                              hipStream_t stream) {
  const float* x   = (const float*)d_in[0];
  // d_in[1] = mask (deterministic causal triu(k=1) -> handled arithmetically)
  const float* Wq  = (const float*)d_in[2];
  const float* Wk  = (const float*)d_in[3];
  const float* Wv  = (const float*)d_in[4];
  const float* Wo  = (const float*)d_in[5];
  const float* rs  = (const float*)d_in[6];
  const int*   po  = (const int*)d_in[7];
  float* out = (float*)d_out;

  u16* ws    = (u16*)d_ws;
  u16* xb    = ws;                       // [2048][2048]      bf16 (dead after gemm1; reused for rope table)
  u16* wqkv  = xb   + 4194304;           // [3072][2048] B^T  bf16
  u16* wo_t  = wqkv + 6291456;           // [2048][2048] B^T  bf16
  u16* qkv   = wo_t + 4194304;           // [2048][3072]      bf16
  u16* qb    = qkv  + 6291456;           // [16][2048][128]   bf16
  u16* kb2   = qb   + 4194304;           // [4][2048][128]    bf16
  u16* vt    = kb2  + 1048576;           // [4][128][2048]    bf16 (V transposed)
  u16* attn2 = vt   + 1048576;           // [2048][2048]      bf16
  float2* tab = (float2*)xb;             // [2048][64] cos/sin (1 MB, in dead xb region)

  cvt_bf16<<<2048, 256, 0, stream>>>(x, xb, 1048576);
  transpose_cvt<<<dim3(32,32), 256, 0, stream>>>(Wq, wqkv,             2048, 2048);
  transpose_cvt<<<dim3(8, 32), 256, 0, stream>>>(Wk, wqkv + 2048*2048, 512,  2048);
  transpose_cvt<<<dim3(8, 32), 256, 0, stream>>>(Wv, wqkv + 2560*2048, 512,  2048);
  transpose_cvt<<<dim3(32,32), 256, 0, stream>>>(Wo, wo_t,             2048, 2048);

  gemm_bt<true><<<dim3(24,16), 256, 0, stream>>>(xb, wqkv, qkv, 2048, 3072, 2048);
  build_rope_tab<<<512, 256, 0, stream>>>(rs, po, tab);
  rope_kernel<<<2048, 256, 0, stream>>>(qkv, qb, kb2, tab);
  transpose_v<<<dim3(32,2,4), 256, 0, stream>>>(qkv, vt);
  attn_kernel<<<dim3(64,16), 256, 0, stream>>>(qb, kb2, vt, attn2);
  gemm_bt<false><<<dim3(16,16), 256, 0, stream>>>(attn2, wo_t, out, 2048, 2048, 2048);
}